// Round 12
// baseline (148.620 us; speedup 1.0000x reference)
//
#include <hip/hip_runtime.h>
#include <math.h>

// MHAttention: BS=8, D=256, L=1024, H=8, DK=32
// Round 9 (from measured R8e counters: attn 47us, MfmaUtil 6.8%, VALU 47%,
// 4.19M LDS bank conflicts, FETCH ideal at 11.4MB -> latency/LDS-bound):
// (1) attn: K/V LDS staging DELETED (per-bh K/V = 128KB, L2-resident; XCD
//     remap pins it to one L2). Frags read straight from global. No
//     __syncthreads at all (16 barriers removed), no double-buffer, LDS
//     drops 28KB -> 9KB (wave-private P buffer only).
// (2) outproj: reverted to the LDS-staged R7 structure (zero-LDS variant
//     was part of the +15us regression); Wp tile staged from f16 wp_h.
// (3) proj + exp2 domain kept from R8e (compiled, passed, absmax 0.0156).

constexpr int cD  = 256;
constexpr int cL  = 1024;
constexpr int cH  = 8;
constexpr int cDK = 32;
constexpr float kLog2e = 1.44269504088896f;

typedef _Float16 f16;
typedef __attribute__((ext_vector_type(8))) _Float16 h8;   // 8 f16 = 4 VGPRs
typedef __attribute__((ext_vector_type(4))) _Float16 h4;   // 8 B
typedef __attribute__((ext_vector_type(4))) float f4v;     // MFMA C/D

// ---------------------------------------------------------------------------
// Kernel 1: Q,K,V projections via MFMA. grid 1088 = 1024 proj blocks
// (bh:64, lt:16 of 64 l) + 64 tail blocks converting Wp -> f16.
// Outputs: qp[bh][r][c] (B-frag layout, PRE-SCALED by log2e), kp[bh][e][c]
// masked, vp[bh][c][e], wp_h = f16(Wp).
// ---------------------------------------------------------------------------
__global__ __launch_bounds__(256, 4) void proj_qkv_kernel(
    const float* __restrict__ queries, const float* __restrict__ keys,
    const float* __restrict__ values, const float* __restrict__ mask,
    const float* __restrict__ Wq, const float* __restrict__ Wk,
    const float* __restrict__ Wv, const float* __restrict__ Wp,
    f16* __restrict__ qp_h, f16* __restrict__ kp_h, f16* __restrict__ vp_h,
    f16* __restrict__ wp_h)
{
    const int t   = threadIdx.x;
    const int bid = blockIdx.x;

    if (bid >= 1024) {   // ---- tail: convert Wp (256x256 fp32) to f16 ----
        const int idx = ((bid - 1024) * 256 + t) * 4;
        float4 f = *reinterpret_cast<const float4*>(&Wp[idx]);
        h4 o; o[0] = (f16)f.x; o[1] = (f16)f.y; o[2] = (f16)f.z; o[3] = (f16)f.w;
        *reinterpret_cast<h4*>(&wp_h[idx]) = o;
        return;
    }

    __shared__ __align__(16) f16 wlds[3][32 * 40];   // rows padded 32->40 f16

    const int lt   = bid & 15;
    const int bh   = bid >> 4;
    const int h    = bh & 7;
    const int b    = bh >> 3;
    const int l0   = lt * 64;
    const int lane = t & 63, w = t >> 6, ln15 = lane & 15, lq = lane >> 4;
    const int l    = l0 + w * 16 + ln15;     // this lane's l (MFMA n-index)

    // ---- stage W head-slices once: 3 x 1024 floats, coalesced float4 ----
    {
        const float* Wsrc[3] = {Wq, Wk, Wv};
        const int r = t >> 3, c = (t & 7) * 4;      // t*4 = r*32 + c
        #pragma unroll
        for (int m = 0; m < 3; ++m) {
            float4 f = *reinterpret_cast<const float4*>(&Wsrc[m][h * 1024 + t * 4]);
            h4 o; o[0] = (f16)f.x; o[1] = (f16)f.y; o[2] = (f16)f.z; o[3] = (f16)f.w;
            *reinterpret_cast<h4*>(&wlds[m][r * 40 + c]) = o;
        }
    }
    __syncthreads();

    const float mk = mask[b * cL + l];
    const size_t xbase = ((size_t)(b * cD + h * cDK)) * cL + l;   // + j*cL

    const float* Xs[3] = {queries, keys, values};
    f4v d0[3], d1[3];

    #pragma unroll
    for (int m = 0; m < 3; ++m) {
        const float* __restrict__ X = Xs[m];
        h8 bx;
        #pragma unroll
        for (int i = 0; i < 8; ++i)
            bx[i] = (f16)X[xbase + (size_t)(lq * 8 + i) * cL];
        h8 a0 = *reinterpret_cast<const h8*>(&wlds[m][ln15 * 40 + lq * 8]);
        h8 a1 = *reinterpret_cast<const h8*>(&wlds[m][(16 + ln15) * 40 + lq * 8]);
        f4v z = {0.f, 0.f, 0.f, 0.f};
        d0[m] = __builtin_amdgcn_mfma_f32_16x16x32_f16(a0, bx, z, 0, 0, 0);
        d1[m] = __builtin_amdgcn_mfma_f32_16x16x32_f16(a1, bx, z, 0, 0, 0);
    }

    // ---- Q: [r=l][c], fp16, pre-scaled by log2e (feeds exp2 softmax) ----
    {
        const size_t qb = ((size_t)bh * cL + l) * cDK;
        h4 o0, o1;
        #pragma unroll
        for (int i = 0; i < 4; ++i) {
            o0[i] = (f16)(d0[0][i] * kLog2e);
            o1[i] = (f16)(d1[0][i] * kLog2e);
        }
        *reinterpret_cast<h4*>(&qp_h[qb + lq * 4])      = o0;
        *reinterpret_cast<h4*>(&qp_h[qb + 16 + lq * 4]) = o1;
    }
    // ---- K: [e=l][c], masked ----
    {
        const size_t kb = ((size_t)bh * cL + l) * cDK;
        h4 o0, o1;
        #pragma unroll
        for (int i = 0; i < 4; ++i) {
            o0[i] = (f16)(d0[1][i] * mk);
            o1[i] = (f16)(d1[1][i] * mk);
        }
        *reinterpret_cast<h4*>(&kp_h[kb + lq * 4])      = o0;
        *reinterpret_cast<h4*>(&kp_h[kb + 16 + lq * 4]) = o1;
    }
    // ---- V: [c][e=l] ----
    {
        const size_t vb = (size_t)bh * cDK * cL + l;
        #pragma unroll
        for (int i = 0; i < 4; ++i) {
            vp_h[vb + (size_t)(lq * 4 + i) * cL]      = (f16)d0[2][i];
            vp_h[vb + (size_t)(16 + lq * 4 + i) * cL] = (f16)d1[2][i];
        }
    }
}

// ---------------------------------------------------------------------------
// Kernel 2: fused attention, fp16 MFMA, NO K/V LDS staging, NO barriers.
// Block = (b, h, 64-row strip), 4 waves; wave w owns rows r = w*16 + ln15.
// grid 1024; bid = strip*64 + bh -> bid%8 == h%8: all 16 strips of one
// (b,h) on ONE XCD; its 128KB K/V is L2-resident and frags are read
// straight from global each tile. Only LDS: wave-private P buffer (9KB).
// Logits arrive pre-scaled by log2e (Q scaled at projection) -> exp2f.
// ---------------------------------------------------------------------------
__global__ __launch_bounds__(256, 4) void attn_kernel(
    const float* __restrict__ mask, const f16* __restrict__ qp_h,
    const f16* __restrict__ kp_h, const f16* __restrict__ vp_h,
    f16* __restrict__ val_h)
{
    __shared__ __align__(16) f16 pbf[64 * 72];   // [64r][72] 9216 B, rows 144 B

    const int t     = threadIdx.x;
    const int bid   = blockIdx.x;
    const int bh    = bid & 63;        // XCD = bid%8 = h%8 (L2 locality)
    const int strip = bid >> 6;
    const int b     = bh >> 3;
    const int r0    = strip * 64;
    const int lane  = t & 63;
    const int w     = t >> 6;
    const int ln15  = lane & 15;
    const int lq    = lane >> 4;

    const size_t kvbase = ((size_t)bh) * 32768;             // f16 units

    // ---- persistent B-frag: this lane's q row, straight from global ----
    const h8 qf = *reinterpret_cast<const h8*>(
        &qp_h[((size_t)bh * cL + r0 + w * 16 + ln15) * cDK + lq * 8]);

    f4v o0 = {0.f, 0.f, 0.f, 0.f}, o1 = {0.f, 0.f, 0.f, 0.f};
    float mo = -INFINITY, lrp = 0.f;   // lrp: per-lane partial (16 e-cols)
    const int prow = (w * 16 + ln15) * 72;

    // V row bases for this lane (A-frag rows c=ln15 and c=16+ln15)
    const size_t vrow0 = kvbase + (size_t)ln15 * cL + lq * 8;
    const size_t vrow1 = kvbase + (size_t)(16 + ln15) * cL + lq * 8;

    for (int et = 0; et < 16; ++et) {
        const int e0 = et * 64;

        // mask for this tile: broadcast global reads (L1-hot)
        float4 mk4[4];
        #pragma unroll
        for (int es = 0; es < 4; ++es)
            mk4[es] = *reinterpret_cast<const float4*>(
                &mask[b * cL + e0 + es * 16 + lq * 4]);

        // ---- S^T tiles: D[e][r] = K[e][c] x Q^T[c][r]; K-frag from L2 ----
        f4v sA[4];
        #pragma unroll
        for (int es = 0; es < 4; ++es) {
            const h8 kf = *reinterpret_cast<const h8*>(
                &kp_h[kvbase + (size_t)(e0 + es * 16 + ln15) * cDK + lq * 8]);
            f4v z = {0.f, 0.f, 0.f, 0.f};
            sA[es] = __builtin_amdgcn_mfma_f32_16x16x32_f16(kf, qf, z, 0, 0, 0);
        }

        // ---- softmax: lane owns row r = w*16+ln15 (scalar stats) ----
        float tm = -INFINITY;
        #pragma unroll
        for (int es = 0; es < 4; ++es) {
            float r01 = fmaxf(sA[es][0], sA[es][1]);
            float r23 = fmaxf(sA[es][2], sA[es][3]);
            tm = fmaxf(tm, fmaxf(r01, r23));
        }
        tm = fmaxf(tm, __shfl_xor(tm, 16));
        tm = fmaxf(tm, __shfl_xor(tm, 32));
        const float mn = fmaxf(mo, tm);
        const float al = exp2f(mo - mn);      // first tile: 2^(-inf) = 0
        mo = mn;
        o0[0] *= al; o0[1] *= al; o0[2] *= al; o0[3] *= al;
        o1[0] *= al; o1[1] *= al; o1[2] *= al; o1[3] *= al;

        float ps = 0.f;
        #pragma unroll
        for (int es = 0; es < 4; ++es) {
            // p = mask * exp2(s - mn): inner mask-mul redundant (masked s=0<=mn)
            float p0 = mk4[es].x * exp2f(sA[es][0] - mn);
            float p1 = mk4[es].y * exp2f(sA[es][1] - mn);
            float p2 = mk4[es].z * exp2f(sA[es][2] - mn);
            float p3 = mk4[es].w * exp2f(sA[es][3] - mn);
            ps += (p0 + p1) + (p2 + p3);
            h4 pk; pk[0] = (f16)p0; pk[1] = (f16)p1; pk[2] = (f16)p2; pk[3] = (f16)p3;
            *reinterpret_cast<h4*>(&pbf[prow + es * 16 + lq * 4]) = pk;  // wave-private
        }
        lrp = lrp * al + ps;   // shuffle-reduce deferred to epilogue

        // ---- PV: o^T[c][r] += V[c][e] x P^T[e][r]; V-frags from L2 ----
        #pragma unroll
        for (int ch = 0; ch < 2; ++ch) {
            h8 pf  = *reinterpret_cast<const h8*>(&pbf[prow + ch * 32 + lq * 8]);
            h8 va0 = *reinterpret_cast<const h8*>(&vp_h[vrow0 + e0 + ch * 32]);
            h8 va1 = *reinterpret_cast<const h8*>(&vp_h[vrow1 + e0 + ch * 32]);
            o0 = __builtin_amdgcn_mfma_f32_16x16x32_f16(va0, pf, o0, 0, 0, 0);
            o1 = __builtin_amdgcn_mfma_f32_16x16x32_f16(va1, pf, o1, 0, 0, 0);
        }
    }

    // ---- epilogue: complete row-sum, divide, store ----
    {
        float lr = lrp;
        lr += __shfl_xor(lr, 16);
        lr += __shfl_xor(lr, 32);
        const float linv = 1.0f / (lr + 1e-8f);
        const int h = bh & 7;
        const size_t obase = ((size_t)(b * cL + r0 + w * 16 + ln15)) * cD + h * cDK;
        h4 q0, q1;
        #pragma unroll
        for (int i = 0; i < 4; ++i) {
            q0[i] = (f16)(o0[i] * linv);
            q1[i] = (f16)(o1[i] * linv);
        }
        *reinterpret_cast<h4*>(&val_h[obase + lq * 4])      = q0;
        *reinterpret_cast<h4*>(&val_h[obase + 16 + lq * 4]) = q1;
    }
}

// ---------------------------------------------------------------------------
// Kernel 3: out[b][l][i] = mask[b][l] * (sum_j Wp[i][j]*val[b][l][j] + bp[i])
// fp16 MFMA, LDS-staged (R7 structure; zero-LDS variant regressed).
// grid 512 = (b:8, lt:16 of 64 l, it:4 of 64 i), block 256.
// ---------------------------------------------------------------------------
__global__ __launch_bounds__(256, 2) void outproj_kernel(
    const f16* __restrict__ val_h, const f16* __restrict__ wp_h,
    const float* __restrict__ bp, const float* __restrict__ mask,
    float* __restrict__ out)
{
    __shared__ __align__(16) f16 vt[64 * 264];    // [64 l][264 j-pad] rows 528 B
    __shared__ __align__(16) f16 wpb[64 * 264];   // [64 i][264 j-pad]
    __shared__ float mrow[64];

    const int t    = threadIdx.x;
    const int bid  = blockIdx.x;
    const int it   = bid & 3;
    const int lt   = (bid >> 2) & 15;
    const int b    = bid >> 6;
    const int l0   = lt * 64, i0 = it * 64;
    const int lane = t & 63, w = t >> 6, ln15 = lane & 15, lq = lane >> 4;

    {   // stage val tile; row = t&63 fast -> conflict-free LDS writes
        int row = t & 63, seg = (t >> 6) * 64;
        const f16* src = &val_h[((size_t)(b * cL + l0 + row)) * cD + seg];
        #pragma unroll
        for (int k = 0; k < 8; ++k)
            *reinterpret_cast<h8*>(&vt[row * 264 + seg + k * 8]) =
                *reinterpret_cast<const h8*>(src + k * 8);
    }
    {   // stage Wp tile (already f16 in wp_h)
        int row = t & 63, seg = (t >> 6) * 64;
        const f16* src = &wp_h[((size_t)(i0 + row)) * cD + seg];
        #pragma unroll
        for (int k = 0; k < 8; ++k)
            *reinterpret_cast<h8*>(&wpb[row * 264 + seg + k * 8]) =
                *reinterpret_cast<const h8*>(src + k * 8);
    }
    if (t < 64) mrow[t] = mask[b * cL + l0 + t];
    __syncthreads();

    f4v acc[4] = {{0.f, 0.f, 0.f, 0.f}, {0.f, 0.f, 0.f, 0.f},
                  {0.f, 0.f, 0.f, 0.f}, {0.f, 0.f, 0.f, 0.f}};
    #pragma unroll
    for (int kc = 0; kc < 8; ++kc) {
        h8 aA = *reinterpret_cast<const h8*>(&vt[(w * 16 + ln15) * 264 + kc * 32 + lq * 8]);
        #pragma unroll
        for (int ti = 0; ti < 4; ++ti) {
            h8 bB = *reinterpret_cast<const h8*>(&wpb[(ti * 16 + ln15) * 264 + kc * 32 + lq * 8]);
            acc[ti] = __builtin_amdgcn_mfma_f32_16x16x32_f16(aA, bB, acc[ti], 0, 0, 0);
        }
    }

    float mk[4];
    #pragma unroll
    for (int rg = 0; rg < 4; ++rg) mk[rg] = mrow[w * 16 + lq * 4 + rg];
    #pragma unroll
    for (int ti = 0; ti < 4; ++ti) {
        float bpv = bp[i0 + ti * 16 + ln15];
        #pragma unroll
        for (int rg = 0; rg < 4; ++rg) {
            int l = l0 + w * 16 + lq * 4 + rg;
            out[((size_t)(b * cL + l)) * cD + i0 + ti * 16 + ln15] =
                (acc[ti][rg] + bpv) * mk[rg];
        }
    }
}

// ---------------------------------------------------------------------------
extern "C" void kernel_launch(void* const* d_in, const int* in_sizes, int n_in,
                              void* d_out, int out_size, void* d_ws, size_t ws_size,
                              hipStream_t stream) {
    const float* queries = (const float*)d_in[0];
    const float* keys    = (const float*)d_in[1];
    const float* values  = (const float*)d_in[2];
    const float* mask    = (const float*)d_in[3];
    const float* Wq      = (const float*)d_in[4];
    const float* Wk      = (const float*)d_in[5];
    const float* Wv      = (const float*)d_in[6];
    const float* Wp      = (const float*)d_in[7];
    const float* bp      = (const float*)d_in[8];
    float* out = (float*)d_out;

    // ws: qp 4MB | kp 4MB | vp 4MB | val 4MB | wp_h 128KB
    char* wsb = (char*)d_ws;
    f16* qp_h  = (f16*)(wsb);
    f16* kp_h  = (f16*)(wsb + (4u << 20));
    f16* vp_h  = (f16*)(wsb + (8u << 20));
    f16* val_h = (f16*)(wsb + (12u << 20));
    f16* wp_h  = (f16*)(wsb + (16u << 20));

    proj_qkv_kernel<<<dim3(1088), dim3(256), 0, stream>>>(
        queries, keys, values, mask, Wq, Wk, Wv, Wp, qp_h, kp_h, vp_h, wp_h);
    attn_kernel<<<dim3(1024), dim3(256), 0, stream>>>(
        mask, qp_h, kp_h, vp_h, val_h);
    outproj_kernel<<<dim3(512), dim3(256), 0, stream>>>(val_h, wp_h, bp, mask, out);
}

// Round 15
// 132.523 us; speedup vs baseline: 1.1215x; 1.1215x over previous
//
#include <hip/hip_runtime.h>
#include <math.h>

// MHAttention: BS=8, D=256, L=1024, H=8, DK=32
// Round 10. Decomposition across R7(127.3)/R8e(142.1)/R9(148.6):
//   fill ~47us/iter is a fixed floor; R7 proj+outproj ~33us; R8's proj-LDS
//   + zero-LDS outproj regressed that to ~48; R9's attn de-staging regressed
//   attn 47->58.7 (latency-bound: MfmaUtil 6.8->5.5, VALU 47->38 -- the LDS
//   dbuf prefetch was hiding L2 latency; bank conflicts were 2-way/free).
// => proj & outproj REVERTED TO EXACT R7. attn = R8e staged structure plus
//    two VALU cuts aimed at the measured 47% VALUBusy:
// (1) mask folded into QK^T as MFMA C-init bias (mbias: 0 / -30000, built
//     by one proj tail block): masked logits -> -30000 -> exp2f == 0.
//     Deletes 16 mask-muls/tile/lane; mask loads unchanged (read mbias).
// (2) defer-max, THR=8 (wave-uniform __any): skip o/lr rescale when running
//     max grew <= 8; p <= 2^8 fits f16. Rescale runs only on first tiles.
// Kept: XCD remap (bh=bid&63), exp2 domain (Q pre-scaled by log2e in proj).

constexpr int cD  = 256;
constexpr int cL  = 1024;
constexpr int cH  = 8;
constexpr int cDK = 32;
constexpr float kLog2e = 1.44269504088896f;

typedef _Float16 f16;
typedef __attribute__((ext_vector_type(8))) _Float16 h8;   // 8 f16 = 4 VGPRs
typedef __attribute__((ext_vector_type(4))) _Float16 h4;   // 8 B
typedef __attribute__((ext_vector_type(4))) float f4v;     // MFMA C/D

// ---------------------------------------------------------------------------
// Kernel 1: Q,K,V projections via MFMA (R7 structure: zero LDS, W rows
// gathered from global -- L1-hot). grid 1025 = 1024 proj blocks (bh:64,
// lt:16 of 64 l) + 1 tail block building mbias[b][e] = mask?0:-30000.
// Outputs: qp[bh][r][c] (B-frag layout, PRE-SCALED by log2e), kp[bh][e][c]
// masked, vp[bh][c][e], mbias (8x1024 f32).
// ---------------------------------------------------------------------------
__global__ __launch_bounds__(256, 4) void proj_qkv_kernel(
    const float* __restrict__ queries, const float* __restrict__ keys,
    const float* __restrict__ values, const float* __restrict__ mask,
    const float* __restrict__ Wq, const float* __restrict__ Wk,
    const float* __restrict__ Wv, f16* __restrict__ qp_h,
    f16* __restrict__ kp_h, f16* __restrict__ vp_h,
    float* __restrict__ mbias)
{
    const int t   = threadIdx.x;
    const int bid = blockIdx.x;

    if (bid >= 1024) {   // ---- tail: mbias = mask ? 0 : -30000 ----
        for (int i = t; i < cH * cL; i += 256)   // 8*1024 = BS*L
            mbias[i] = (mask[i] > 0.f) ? 0.f : -30000.0f;
        return;
    }

    const int lt   = bid & 15;
    const int bh   = bid >> 4;
    const int h    = bh & 7;
    const int b    = bh >> 3;
    const int l0   = lt * 64;
    const int lane = t & 63, w = t >> 6, ln15 = lane & 15, lq = lane >> 4;
    const int l    = l0 + w * 16 + ln15;     // this lane's l (MFMA n-index)

    const float mk = mask[b * cL + l];
    const size_t xbase = ((size_t)(b * cD + h * cDK)) * cL + l;   // + j*cL
    const int    wbase = h * cDK * cDK + lq * 8;                  // + c*cDK

    const float* Xs[3] = {queries, keys, values};
    const float* Ws[3] = {Wq, Wk, Wv};
    f4v d0[3], d1[3];

    #pragma unroll
    for (int m = 0; m < 3; ++m) {
        const float* __restrict__ X = Xs[m];
        const float* __restrict__ W = Ws[m];
        h8 bx, a0, a1;
        #pragma unroll
        for (int i = 0; i < 8; ++i)
            bx[i] = (f16)X[xbase + (size_t)(lq * 8 + i) * cL];
        #pragma unroll
        for (int i = 0; i < 8; ++i) {
            a0[i] = (f16)W[wbase + ln15 * cDK + i];
            a1[i] = (f16)W[wbase + (16 + ln15) * cDK + i];
        }
        f4v z = {0.f, 0.f, 0.f, 0.f};
        d0[m] = __builtin_amdgcn_mfma_f32_16x16x32_f16(a0, bx, z, 0, 0, 0);
        d1[m] = __builtin_amdgcn_mfma_f32_16x16x32_f16(a1, bx, z, 0, 0, 0);
    }

    // ---- Q: [r=l][c], fp16, pre-scaled by log2e (feeds exp2 softmax) ----
    {
        const size_t qb = ((size_t)bh * cL + l) * cDK;
        h4 o0, o1;
        #pragma unroll
        for (int i = 0; i < 4; ++i) {
            o0[i] = (f16)(d0[0][i] * kLog2e);
            o1[i] = (f16)(d1[0][i] * kLog2e);
        }
        *reinterpret_cast<h4*>(&qp_h[qb + lq * 4])      = o0;
        *reinterpret_cast<h4*>(&qp_h[qb + 16 + lq * 4]) = o1;
    }
    // ---- K: [e=l][c], masked ----
    {
        const size_t kb = ((size_t)bh * cL + l) * cDK;
        h4 o0, o1;
        #pragma unroll
        for (int i = 0; i < 4; ++i) {
            o0[i] = (f16)(d0[1][i] * mk);
            o1[i] = (f16)(d1[1][i] * mk);
        }
        *reinterpret_cast<h4*>(&kp_h[kb + lq * 4])      = o0;
        *reinterpret_cast<h4*>(&kp_h[kb + 16 + lq * 4]) = o1;
    }
    // ---- V: [c][e=l] ----
    {
        const size_t vb = (size_t)bh * cDK * cL + l;
        #pragma unroll
        for (int i = 0; i < 4; ++i) {
            vp_h[vb + (size_t)(lq * 4 + i) * cL]      = (f16)d0[2][i];
            vp_h[vb + (size_t)(16 + lq * 4 + i) * cL] = (f16)d1[2][i];
        }
    }
}

// ---------------------------------------------------------------------------
// Kernel 2: fused attention, fp16 MFMA. R8e staged/double-buffered structure
// (measured 47us; destaged variant was 58.7 -- latency-bound). Block =
// (b, h, 64-row strip), 4 waves; wave w owns rows r = w*16 + ln15.
// grid 1024; bid = strip*64 + bh -> bid%8 == h%8: one XCD per (b,h).
// NEW: mask enters as MFMA C-init bias (mbias), p = exp2f(s - mo) with
// defer-max (THR=8). 28 KB LDS -> 5 blocks/CU.
// ---------------------------------------------------------------------------
__global__ __launch_bounds__(256, 5) void attn_kernel(
    const float* __restrict__ mbias, const f16* __restrict__ qp_h,
    const f16* __restrict__ kp_h, const f16* __restrict__ vp_h,
    f16* __restrict__ val_h)
{
    __shared__ __align__(16) char smem[28672];
    f16* ks  = (f16*)smem;             // [2][64e][40]  10240 B, rows 80 B
    f16* vsb = (f16*)(smem + 10240);   // [2][32c][72]   9216 B, rows 144 B
    f16* pbf = (f16*)(smem + 19456);   // [64r][72]      9216 B, rows 144 B

    const int t     = threadIdx.x;
    const int bid   = blockIdx.x;
    const int bh    = bid & 63;        // XCD = bid%8 = h%8 (L2 locality)
    const int strip = bid >> 6;
    const int b     = bh >> 3;
    const int r0    = strip * 64;
    const int lane  = t & 63;
    const int w     = t >> 6;
    const int ln15  = lane & 15;
    const int lq    = lane >> 4;

    const size_t kvbase = ((size_t)bh) * 32768;             // f16 units
    const int se = t >> 2, sb = (t & 3) * 8;                // K staging coords
    const int vc = t >> 3, veb = (t & 7) * 8;               // V staging coords

    // ---- persistent B-frag: this lane's q row, straight from global ----
    const h8 qf = *reinterpret_cast<const h8*>(
        &qp_h[((size_t)bh * cL + r0 + w * 16 + ln15) * cDK + lq * 8]);

    // ---- stage tile 0 into buf 0 ----
    {
        h8 kh = *reinterpret_cast<const h8*>(&kp_h[kvbase + se * 32 + sb]);
        *reinterpret_cast<h8*>(&ks[se * 40 + sb]) = kh;
        h8 vv = *reinterpret_cast<const h8*>(&vp_h[kvbase + vc * 1024 + veb]);
        *reinterpret_cast<h8*>(&vsb[vc * 72 + veb]) = vv;
    }

    f4v o0 = {0.f, 0.f, 0.f, 0.f}, o1 = {0.f, 0.f, 0.f, 0.f};
    float mo = -INFINITY, lrp = 0.f;   // lrp: per-lane partial (16 e-cols)
    const int prow  = (w * 16 + ln15) * 72;
    const int vsoff = ln15 * 72 + lq * 8;

    for (int et = 0; et < 16; ++et) {
        __syncthreads();        // tile et visible in buf pp
        const int pp = et & 1;
        const bool pre = (et < 15);
        h8 khp, vvp;
        if (pre) {              // early global loads for tile et+1
            const int e0n = (et + 1) * 64;
            khp = *reinterpret_cast<const h8*>(&kp_h[kvbase + (e0n + se) * 32 + sb]);
            vvp = *reinterpret_cast<const h8*>(&vp_h[kvbase + vc * 1024 + e0n + veb]);
        }
        // mask-bias for this tile (0 or -30000 per e): feeds MFMA C-init
        float4 mk4[4];
        #pragma unroll
        for (int es = 0; es < 4; ++es)
            mk4[es] = *reinterpret_cast<const float4*>(
                &mbias[b * cL + et * 64 + es * 16 + lq * 4]);

        // ---- S^T tiles: D[e][r] = K[e][c] x Q^T[c][r] + mbias[e] ----
        f4v sA[4];
        #pragma unroll
        for (int es = 0; es < 4; ++es) {
            const h8 kf = *reinterpret_cast<const h8*>(
                &ks[pp * 2560 + (es * 16 + ln15) * 40 + lq * 8]);
            f4v cin = {mk4[es].x, mk4[es].y, mk4[es].z, mk4[es].w};
            sA[es] = __builtin_amdgcn_mfma_f32_16x16x32_f16(kf, qf, cin, 0, 0, 0);
        }

        // ---- softmax stats: lane owns row r = w*16+ln15 ----
        float tm = -INFINITY;
        #pragma unroll
        for (int es = 0; es < 4; ++es) {
            float r01 = fmaxf(sA[es][0], sA[es][1]);
            float r23 = fmaxf(sA[es][2], sA[es][3]);
            tm = fmaxf(tm, fmaxf(r01, r23));
        }
        tm = fmaxf(tm, __shfl_xor(tm, 16));
        tm = fmaxf(tm, __shfl_xor(tm, 32));
        // defer-max: rescale only if some row's max grew past mo+8;
        // otherwise p = exp2(s - mo) <= 2^8 still fits f16.
        if (__any(tm > mo + 8.0f)) {
            const float mn = fmaxf(mo, tm);
            const float al = exp2f(mo - mn);  // first tile: 2^(-inf) = 0
            o0[0] *= al; o0[1] *= al; o0[2] *= al; o0[3] *= al;
            o1[0] *= al; o1[1] *= al; o1[2] *= al; o1[3] *= al;
            lrp *= al;
            mo = mn;
        }

        float ps = 0.f;
        #pragma unroll
        for (int es = 0; es < 4; ++es) {
            // masked e: s = 0 - 30000 -> exp2f underflows to exactly 0
            float p0 = exp2f(sA[es][0] - mo);
            float p1 = exp2f(sA[es][1] - mo);
            float p2 = exp2f(sA[es][2] - mo);
            float p3 = exp2f(sA[es][3] - mo);
            ps += (p0 + p1) + (p2 + p3);
            h4 pk; pk[0] = (f16)p0; pk[1] = (f16)p1; pk[2] = (f16)p2; pk[3] = (f16)p3;
            *reinterpret_cast<h4*>(&pbf[prow + es * 16 + lq * 4]) = pk;  // wave-private
        }
        lrp += ps;   // shuffle-reduce deferred to epilogue

        // ---- PV: o^T[c][r] += V[c][e] x P^T[e][r] (same-wave, no barrier) ----
        #pragma unroll
        for (int ch = 0; ch < 2; ++ch) {
            h8 pf  = *reinterpret_cast<const h8*>(&pbf[prow + ch * 32 + lq * 8]);
            h8 va0 = *reinterpret_cast<const h8*>(&vsb[pp * 2304 + vsoff + ch * 32]);
            h8 va1 = *reinterpret_cast<const h8*>(&vsb[pp * 2304 + vsoff + ch * 32 + 1152]);
            o0 = __builtin_amdgcn_mfma_f32_16x16x32_f16(va0, pf, o0, 0, 0, 0);
            o1 = __builtin_amdgcn_mfma_f32_16x16x32_f16(va1, pf, o1, 0, 0, 0);
        }

        // ---- late LDS writes: publish tile et+1 into buf pp^1 ----
        if (pre) {
            *reinterpret_cast<h8*>(&ks[(pp ^ 1) * 2560 + se * 40 + sb]) = khp;
            *reinterpret_cast<h8*>(&vsb[(pp ^ 1) * 2304 + vc * 72 + veb]) = vvp;
        }
    }

    // ---- epilogue: complete row-sum, divide, store ----
    {
        float lr = lrp;
        lr += __shfl_xor(lr, 16);
        lr += __shfl_xor(lr, 32);
        const float linv = 1.0f / (lr + 1e-8f);
        const int h = bh & 7;
        const size_t obase = ((size_t)(b * cL + r0 + w * 16 + ln15)) * cD + h * cDK;
        h4 q0, q1;
        #pragma unroll
        for (int i = 0; i < 4; ++i) {
            q0[i] = (f16)(o0[i] * linv);
            q1[i] = (f16)(o1[i] * linv);
        }
        *reinterpret_cast<h4*>(&val_h[obase + lq * 4])      = q0;
        *reinterpret_cast<h4*>(&val_h[obase + 16 + lq * 4]) = q1;
    }
}

// ---------------------------------------------------------------------------
// Kernel 3: out[b][l][i] = mask[b][l] * (sum_j Wp[i][j]*val[b][l][j] + bp[i])
// EXACT R7 structure (proven in the 127.3us config). fp16 MFMA.
// grid 512 = (b:8, lt:16 of 64 l, it:4 of 64 i), block 256.
// ---------------------------------------------------------------------------
__global__ __launch_bounds__(256, 2) void outproj_kernel(
    const f16* __restrict__ val_h, const float* __restrict__ Wp,
    const float* __restrict__ bp, const float* __restrict__ mask,
    float* __restrict__ out)
{
    __shared__ __align__(16) f16 vt[64 * 264];    // [64 l][264 j-pad] rows 528 B
    __shared__ __align__(16) f16 wpb[64 * 264];   // [64 i][264 j-pad]
    __shared__ float mrow[64];

    const int t    = threadIdx.x;
    const int bid  = blockIdx.x;
    const int it   = bid & 3;
    const int lt   = (bid >> 2) & 15;
    const int b    = bid >> 6;
    const int l0   = lt * 64, i0 = it * 64;
    const int lane = t & 63, w = t >> 6, ln15 = lane & 15, lq = lane >> 4;

    {   // stage val tile; row = t&63 fast -> conflict-free LDS writes
        int row = t & 63, seg = (t >> 6) * 64;
        const f16* src = &val_h[((size_t)(b * cL + l0 + row)) * cD + seg];
        #pragma unroll
        for (int k = 0; k < 8; ++k)
            *reinterpret_cast<h8*>(&vt[row * 264 + seg + k * 8]) =
                *reinterpret_cast<const h8*>(src + k * 8);
    }
    {   // stage Wp tile (fp32 -> fp16)
        int row = t & 63, seg = (t >> 6) * 64;
        const float* src = &Wp[((size_t)(i0 + row)) * cD + seg];
        #pragma unroll
        for (int k = 0; k < 8; ++k) {
            float4 f0 = *reinterpret_cast<const float4*>(src + k * 8);
            float4 f1 = *reinterpret_cast<const float4*>(src + k * 8 + 4);
            h8 hv;
            hv[0] = (f16)f0.x; hv[1] = (f16)f0.y; hv[2] = (f16)f0.z; hv[3] = (f16)f0.w;
            hv[4] = (f16)f1.x; hv[5] = (f16)f1.y; hv[6] = (f16)f1.z; hv[7] = (f16)f1.w;
            *reinterpret_cast<h8*>(&wpb[row * 264 + seg + k * 8]) = hv;
        }
    }
    if (t < 64) mrow[t] = mask[b * cL + l0 + t];
    __syncthreads();

    f4v acc[4] = {{0.f, 0.f, 0.f, 0.f}, {0.f, 0.f, 0.f, 0.f},
                  {0.f, 0.f, 0.f, 0.f}, {0.f, 0.f, 0.f, 0.f}};
    #pragma unroll
    for (int kc = 0; kc < 8; ++kc) {
        h8 aA = *reinterpret_cast<const h8*>(&vt[(w * 16 + ln15) * 264 + kc * 32 + lq * 8]);
        #pragma unroll
        for (int ti = 0; ti < 4; ++ti) {
            h8 bB = *reinterpret_cast<const h8*>(&wpb[(ti * 16 + ln15) * 264 + kc * 32 + lq * 8]);
            acc[ti] = __builtin_amdgcn_mfma_f32_16x16x32_f16(aA, bB, acc[ti], 0, 0, 0);
        }
    }

    float mk[4];
    #pragma unroll
    for (int rg = 0; rg < 4; ++rg) mk[rg] = mrow[w * 16 + lq * 4 + rg];
    #pragma unroll
    for (int ti = 0; ti < 4; ++ti) {
        float bpv = bp[i0 + ti * 16 + ln15];
        #pragma unroll
        for (int rg = 0; rg < 4; ++rg) {
            int l = l0 + w * 16 + lq * 4 + rg;
            out[((size_t)(b * cL + l)) * cD + i0 + ti * 16 + ln15] =
                (acc[ti][rg] + bpv) * mk[rg];
        }
    }
}

// ---------------------------------------------------------------------------
extern "C" void kernel_launch(void* const* d_in, const int* in_sizes, int n_in,
                              void* d_out, int out_size, void* d_ws, size_t ws_size,
                              hipStream_t stream) {
    const float* queries = (const float*)d_in[0];
    const float* keys    = (const float*)d_in[1];
    const float* values  = (const float*)d_in[2];
    const float* mask    = (const float*)d_in[3];
    const float* Wq      = (const float*)d_in[4];
    const float* Wk      = (const float*)d_in[5];
    const float* Wv      = (const float*)d_in[6];
    const float* Wp      = (const float*)d_in[7];
    const float* bp      = (const float*)d_in[8];
    float* out = (float*)d_out;

    // ws: qp 4MB | kp 4MB | vp 4MB | val 4MB | mbias 32KB
    char* wsb = (char*)d_ws;
    f16*   qp_h  = (f16*)(wsb);
    f16*   kp_h  = (f16*)(wsb + (4u << 20));
    f16*   vp_h  = (f16*)(wsb + (8u << 20));
    f16*   val_h = (f16*)(wsb + (12u << 20));
    float* mbias = (float*)(wsb + (16u << 20));

    proj_qkv_kernel<<<dim3(1025), dim3(256), 0, stream>>>(
        queries, keys, values, mask, Wq, Wk, Wv, qp_h, kp_h, vp_h, mbias);
    attn_kernel<<<dim3(1024), dim3(256), 0, stream>>>(
        mbias, qp_h, kp_h, vp_h, val_h);
    outproj_kernel<<<dim3(512), dim3(256), 0, stream>>>(val_h, Wp, bp, mask, out);
}

// Round 18
// 130.136 us; speedup vs baseline: 1.1420x; 1.0183x over previous
//
#include <hip/hip_runtime.h>
#include <math.h>

// MHAttention: BS=8, D=256, L=1024, H=8, DK=32
// Round 11 (from R10=132.5us measured, attn <42.4us -- mbias+defer-max
// worked): the ONE regression R10 introduced vs the 127.3 baseline config
// was the mbias tail block -- a SINGLE block grid-striding 8192 elements
// (32 serial latency-bound iters ~8us) that the whole proj dispatch (and
// the stream behind it) waits on. Fixed: tail block deleted; mbias written
// by the 128 proj blocks with h==0 (8 b x 16 lt, each owns a distinct
// (b, l-tile)); lq==0 lanes write 64 elems/block, reusing the loaded mk.
// Everything else byte-identical to R10:
//  - proj/outproj: exact R7 structure (proven 127.3 config).
//  - attn: R8e staged/dbuf + XCD remap + exp2 domain + mbias MFMA-C-init
//    + defer-max THR=8.

constexpr int cD  = 256;
constexpr int cL  = 1024;
constexpr int cH  = 8;
constexpr int cDK = 32;
constexpr float kLog2e = 1.44269504088896f;

typedef _Float16 f16;
typedef __attribute__((ext_vector_type(8))) _Float16 h8;   // 8 f16 = 4 VGPRs
typedef __attribute__((ext_vector_type(4))) _Float16 h4;   // 8 B
typedef __attribute__((ext_vector_type(4))) float f4v;     // MFMA C/D

// ---------------------------------------------------------------------------
// Kernel 1: Q,K,V projections via MFMA (R7 structure: zero LDS, W rows
// gathered from global -- L1-hot). grid 1024 (bh:64, lt:16 of 64 l).
// Blocks with h==0 additionally write mbias[b][l] = mask?0:-30000 for
// their l-tile (lq==0 lanes; each (b,l) covered exactly once).
// Outputs: qp[bh][r][c] (B-frag layout, PRE-SCALED by log2e), kp[bh][e][c]
// masked, vp[bh][c][e], mbias (8x1024 f32).
// ---------------------------------------------------------------------------
__global__ __launch_bounds__(256, 4) void proj_qkv_kernel(
    const float* __restrict__ queries, const float* __restrict__ keys,
    const float* __restrict__ values, const float* __restrict__ mask,
    const float* __restrict__ Wq, const float* __restrict__ Wk,
    const float* __restrict__ Wv, f16* __restrict__ qp_h,
    f16* __restrict__ kp_h, f16* __restrict__ vp_h,
    float* __restrict__ mbias)
{
    const int t   = threadIdx.x;
    const int bid = blockIdx.x;

    const int lt   = bid & 15;
    const int bh   = bid >> 4;
    const int h    = bh & 7;
    const int b    = bh >> 3;
    const int l0   = lt * 64;
    const int lane = t & 63, w = t >> 6, ln15 = lane & 15, lq = lane >> 4;
    const int l    = l0 + w * 16 + ln15;     // this lane's l (MFMA n-index)

    const float mk = mask[b * cL + l];

    // ---- mbias: h==0 blocks cover each (b, l) exactly once ----
    if (h == 0 && lq == 0)
        mbias[b * cL + l] = (mk > 0.f) ? 0.f : -30000.0f;

    const size_t xbase = ((size_t)(b * cD + h * cDK)) * cL + l;   // + j*cL
    const int    wbase = h * cDK * cDK + lq * 8;                  // + c*cDK

    const float* Xs[3] = {queries, keys, values};
    const float* Ws[3] = {Wq, Wk, Wv};
    f4v d0[3], d1[3];

    #pragma unroll
    for (int m = 0; m < 3; ++m) {
        const float* __restrict__ X = Xs[m];
        const float* __restrict__ W = Ws[m];
        h8 bx, a0, a1;
        #pragma unroll
        for (int i = 0; i < 8; ++i)
            bx[i] = (f16)X[xbase + (size_t)(lq * 8 + i) * cL];
        #pragma unroll
        for (int i = 0; i < 8; ++i) {
            a0[i] = (f16)W[wbase + ln15 * cDK + i];
            a1[i] = (f16)W[wbase + (16 + ln15) * cDK + i];
        }
        f4v z = {0.f, 0.f, 0.f, 0.f};
        d0[m] = __builtin_amdgcn_mfma_f32_16x16x32_f16(a0, bx, z, 0, 0, 0);
        d1[m] = __builtin_amdgcn_mfma_f32_16x16x32_f16(a1, bx, z, 0, 0, 0);
    }

    // ---- Q: [r=l][c], fp16, pre-scaled by log2e (feeds exp2 softmax) ----
    {
        const size_t qb = ((size_t)bh * cL + l) * cDK;
        h4 o0, o1;
        #pragma unroll
        for (int i = 0; i < 4; ++i) {
            o0[i] = (f16)(d0[0][i] * kLog2e);
            o1[i] = (f16)(d1[0][i] * kLog2e);
        }
        *reinterpret_cast<h4*>(&qp_h[qb + lq * 4])      = o0;
        *reinterpret_cast<h4*>(&qp_h[qb + 16 + lq * 4]) = o1;
    }
    // ---- K: [e=l][c], masked ----
    {
        const size_t kb = ((size_t)bh * cL + l) * cDK;
        h4 o0, o1;
        #pragma unroll
        for (int i = 0; i < 4; ++i) {
            o0[i] = (f16)(d0[1][i] * mk);
            o1[i] = (f16)(d1[1][i] * mk);
        }
        *reinterpret_cast<h4*>(&kp_h[kb + lq * 4])      = o0;
        *reinterpret_cast<h4*>(&kp_h[kb + 16 + lq * 4]) = o1;
    }
    // ---- V: [c][e=l] ----
    {
        const size_t vb = (size_t)bh * cDK * cL + l;
        #pragma unroll
        for (int i = 0; i < 4; ++i) {
            vp_h[vb + (size_t)(lq * 4 + i) * cL]      = (f16)d0[2][i];
            vp_h[vb + (size_t)(16 + lq * 4 + i) * cL] = (f16)d1[2][i];
        }
    }
}

// ---------------------------------------------------------------------------
// Kernel 2: fused attention, fp16 MFMA. R8e staged/double-buffered structure
// (measured 47us; destaged variant was 58.7 -- latency-bound). Block =
// (b, h, 64-row strip), 4 waves; wave w owns rows r = w*16 + ln15.
// grid 1024; bid = strip*64 + bh -> bid%8 == h%8: one XCD per (b,h).
// mask enters as MFMA C-init bias (mbias), p = exp2f(s - mo) with
// defer-max (THR=8). 28 KB LDS -> 5 blocks/CU. Measured <42.4us in R10.
// ---------------------------------------------------------------------------
__global__ __launch_bounds__(256, 5) void attn_kernel(
    const float* __restrict__ mbias, const f16* __restrict__ qp_h,
    const f16* __restrict__ kp_h, const f16* __restrict__ vp_h,
    f16* __restrict__ val_h)
{
    __shared__ __align__(16) char smem[28672];
    f16* ks  = (f16*)smem;             // [2][64e][40]  10240 B, rows 80 B
    f16* vsb = (f16*)(smem + 10240);   // [2][32c][72]   9216 B, rows 144 B
    f16* pbf = (f16*)(smem + 19456);   // [64r][72]      9216 B, rows 144 B

    const int t     = threadIdx.x;
    const int bid   = blockIdx.x;
    const int bh    = bid & 63;        // XCD = bid%8 = h%8 (L2 locality)
    const int strip = bid >> 6;
    const int b     = bh >> 3;
    const int r0    = strip * 64;
    const int lane  = t & 63;
    const int w     = t >> 6;
    const int ln15  = lane & 15;
    const int lq    = lane >> 4;

    const size_t kvbase = ((size_t)bh) * 32768;             // f16 units
    const int se = t >> 2, sb = (t & 3) * 8;                // K staging coords
    const int vc = t >> 3, veb = (t & 7) * 8;               // V staging coords

    // ---- persistent B-frag: this lane's q row, straight from global ----
    const h8 qf = *reinterpret_cast<const h8*>(
        &qp_h[((size_t)bh * cL + r0 + w * 16 + ln15) * cDK + lq * 8]);

    // ---- stage tile 0 into buf 0 ----
    {
        h8 kh = *reinterpret_cast<const h8*>(&kp_h[kvbase + se * 32 + sb]);
        *reinterpret_cast<h8*>(&ks[se * 40 + sb]) = kh;
        h8 vv = *reinterpret_cast<const h8*>(&vp_h[kvbase + vc * 1024 + veb]);
        *reinterpret_cast<h8*>(&vsb[vc * 72 + veb]) = vv;
    }

    f4v o0 = {0.f, 0.f, 0.f, 0.f}, o1 = {0.f, 0.f, 0.f, 0.f};
    float mo = -INFINITY, lrp = 0.f;   // lrp: per-lane partial (16 e-cols)
    const int prow  = (w * 16 + ln15) * 72;
    const int vsoff = ln15 * 72 + lq * 8;

    for (int et = 0; et < 16; ++et) {
        __syncthreads();        // tile et visible in buf pp
        const int pp = et & 1;
        const bool pre = (et < 15);
        h8 khp, vvp;
        if (pre) {              // early global loads for tile et+1
            const int e0n = (et + 1) * 64;
            khp = *reinterpret_cast<const h8*>(&kp_h[kvbase + (e0n + se) * 32 + sb]);
            vvp = *reinterpret_cast<const h8*>(&vp_h[kvbase + vc * 1024 + e0n + veb]);
        }
        // mask-bias for this tile (0 or -30000 per e): feeds MFMA C-init
        float4 mk4[4];
        #pragma unroll
        for (int es = 0; es < 4; ++es)
            mk4[es] = *reinterpret_cast<const float4*>(
                &mbias[b * cL + et * 64 + es * 16 + lq * 4]);

        // ---- S^T tiles: D[e][r] = K[e][c] x Q^T[c][r] + mbias[e] ----
        f4v sA[4];
        #pragma unroll
        for (int es = 0; es < 4; ++es) {
            const h8 kf = *reinterpret_cast<const h8*>(
                &ks[pp * 2560 + (es * 16 + ln15) * 40 + lq * 8]);
            f4v cin = {mk4[es].x, mk4[es].y, mk4[es].z, mk4[es].w};
            sA[es] = __builtin_amdgcn_mfma_f32_16x16x32_f16(kf, qf, cin, 0, 0, 0);
        }

        // ---- softmax stats: lane owns row r = w*16+ln15 ----
        float tm = -INFINITY;
        #pragma unroll
        for (int es = 0; es < 4; ++es) {
            float r01 = fmaxf(sA[es][0], sA[es][1]);
            float r23 = fmaxf(sA[es][2], sA[es][3]);
            tm = fmaxf(tm, fmaxf(r01, r23));
        }
        tm = fmaxf(tm, __shfl_xor(tm, 16));
        tm = fmaxf(tm, __shfl_xor(tm, 32));
        // defer-max: rescale only if some row's max grew past mo+8;
        // otherwise p = exp2(s - mo) <= 2^8 still fits f16.
        if (__any(tm > mo + 8.0f)) {
            const float mn = fmaxf(mo, tm);
            const float al = exp2f(mo - mn);  // first tile: 2^(-inf) = 0
            o0[0] *= al; o0[1] *= al; o0[2] *= al; o0[3] *= al;
            o1[0] *= al; o1[1] *= al; o1[2] *= al; o1[3] *= al;
            lrp *= al;
            mo = mn;
        }

        float ps = 0.f;
        #pragma unroll
        for (int es = 0; es < 4; ++es) {
            // masked e: s = 0 - 30000 -> exp2f underflows to exactly 0
            float p0 = exp2f(sA[es][0] - mo);
            float p1 = exp2f(sA[es][1] - mo);
            float p2 = exp2f(sA[es][2] - mo);
            float p3 = exp2f(sA[es][3] - mo);
            ps += (p0 + p1) + (p2 + p3);
            h4 pk; pk[0] = (f16)p0; pk[1] = (f16)p1; pk[2] = (f16)p2; pk[3] = (f16)p3;
            *reinterpret_cast<h4*>(&pbf[prow + es * 16 + lq * 4]) = pk;  // wave-private
        }
        lrp += ps;   // shuffle-reduce deferred to epilogue

        // ---- PV: o^T[c][r] += V[c][e] x P^T[e][r] (same-wave, no barrier) ----
        #pragma unroll
        for (int ch = 0; ch < 2; ++ch) {
            h8 pf  = *reinterpret_cast<const h8*>(&pbf[prow + ch * 32 + lq * 8]);
            h8 va0 = *reinterpret_cast<const h8*>(&vsb[pp * 2304 + vsoff + ch * 32]);
            h8 va1 = *reinterpret_cast<const h8*>(&vsb[pp * 2304 + vsoff + ch * 32 + 1152]);
            o0 = __builtin_amdgcn_mfma_f32_16x16x32_f16(va0, pf, o0, 0, 0, 0);
            o1 = __builtin_amdgcn_mfma_f32_16x16x32_f16(va1, pf, o1, 0, 0, 0);
        }

        // ---- late LDS writes: publish tile et+1 into buf pp^1 ----
        if (pre) {
            *reinterpret_cast<h8*>(&ks[(pp ^ 1) * 2560 + se * 40 + sb]) = khp;
            *reinterpret_cast<h8*>(&vsb[(pp ^ 1) * 2304 + vc * 72 + veb]) = vvp;
        }
    }

    // ---- epilogue: complete row-sum, divide, store ----
    {
        float lr = lrp;
        lr += __shfl_xor(lr, 16);
        lr += __shfl_xor(lr, 32);
        const float linv = 1.0f / (lr + 1e-8f);
        const int h = bh & 7;
        const size_t obase = ((size_t)(b * cL + r0 + w * 16 + ln15)) * cD + h * cDK;
        h4 q0, q1;
        #pragma unroll
        for (int i = 0; i < 4; ++i) {
            q0[i] = (f16)(o0[i] * linv);
            q1[i] = (f16)(o1[i] * linv);
        }
        *reinterpret_cast<h4*>(&val_h[obase + lq * 4])      = q0;
        *reinterpret_cast<h4*>(&val_h[obase + 16 + lq * 4]) = q1;
    }
}

// ---------------------------------------------------------------------------
// Kernel 3: out[b][l][i] = mask[b][l] * (sum_j Wp[i][j]*val[b][l][j] + bp[i])
// EXACT R7 structure (proven in the 127.3us config). fp16 MFMA.
// grid 512 = (b:8, lt:16 of 64 l, it:4 of 64 i), block 256.
// ---------------------------------------------------------------------------
__global__ __launch_bounds__(256, 2) void outproj_kernel(
    const f16* __restrict__ val_h, const float* __restrict__ Wp,
    const float* __restrict__ bp, const float* __restrict__ mask,
    float* __restrict__ out)
{
    __shared__ __align__(16) f16 vt[64 * 264];    // [64 l][264 j-pad] rows 528 B
    __shared__ __align__(16) f16 wpb[64 * 264];   // [64 i][264 j-pad]
    __shared__ float mrow[64];

    const int t    = threadIdx.x;
    const int bid  = blockIdx.x;
    const int it   = bid & 3;
    const int lt   = (bid >> 2) & 15;
    const int b    = bid >> 6;
    const int l0   = lt * 64, i0 = it * 64;
    const int lane = t & 63, w = t >> 6, ln15 = lane & 15, lq = lane >> 4;

    {   // stage val tile; row = t&63 fast -> conflict-free LDS writes
        int row = t & 63, seg = (t >> 6) * 64;
        const f16* src = &val_h[((size_t)(b * cL + l0 + row)) * cD + seg];
        #pragma unroll
        for (int k = 0; k < 8; ++k)
            *reinterpret_cast<h8*>(&vt[row * 264 + seg + k * 8]) =
                *reinterpret_cast<const h8*>(src + k * 8);
    }
    {   // stage Wp tile (fp32 -> fp16)
        int row = t & 63, seg = (t >> 6) * 64;
        const float* src = &Wp[((size_t)(i0 + row)) * cD + seg];
        #pragma unroll
        for (int k = 0; k < 8; ++k) {
            float4 f0 = *reinterpret_cast<const float4*>(src + k * 8);
            float4 f1 = *reinterpret_cast<const float4*>(src + k * 8 + 4);
            h8 hv;
            hv[0] = (f16)f0.x; hv[1] = (f16)f0.y; hv[2] = (f16)f0.z; hv[3] = (f16)f0.w;
            hv[4] = (f16)f1.x; hv[5] = (f16)f1.y; hv[6] = (f16)f1.z; hv[7] = (f16)f1.w;
            *reinterpret_cast<h8*>(&wpb[row * 264 + seg + k * 8]) = hv;
        }
    }
    if (t < 64) mrow[t] = mask[b * cL + l0 + t];
    __syncthreads();

    f4v acc[4] = {{0.f, 0.f, 0.f, 0.f}, {0.f, 0.f, 0.f, 0.f},
                  {0.f, 0.f, 0.f, 0.f}, {0.f, 0.f, 0.f, 0.f}};
    #pragma unroll
    for (int kc = 0; kc < 8; ++kc) {
        h8 aA = *reinterpret_cast<const h8*>(&vt[(w * 16 + ln15) * 264 + kc * 32 + lq * 8]);
        #pragma unroll
        for (int ti = 0; ti < 4; ++ti) {
            h8 bB = *reinterpret_cast<const h8*>(&wpb[(ti * 16 + ln15) * 264 + kc * 32 + lq * 8]);
            acc[ti] = __builtin_amdgcn_mfma_f32_16x16x32_f16(aA, bB, acc[ti], 0, 0, 0);
        }
    }

    float mk[4];
    #pragma unroll
    for (int rg = 0; rg < 4; ++rg) mk[rg] = mrow[w * 16 + lq * 4 + rg];
    #pragma unroll
    for (int ti = 0; ti < 4; ++ti) {
        float bpv = bp[i0 + ti * 16 + ln15];
        #pragma unroll
        for (int rg = 0; rg < 4; ++rg) {
            int l = l0 + w * 16 + lq * 4 + rg;
            out[((size_t)(b * cL + l)) * cD + i0 + ti * 16 + ln15] =
                (acc[ti][rg] + bpv) * mk[rg];
        }
    }
}

// ---------------------------------------------------------------------------
extern "C" void kernel_launch(void* const* d_in, const int* in_sizes, int n_in,
                              void* d_out, int out_size, void* d_ws, size_t ws_size,
                              hipStream_t stream) {
    const float* queries = (const float*)d_in[0];
    const float* keys    = (const float*)d_in[1];
    const float* values  = (const float*)d_in[2];
    const float* mask    = (const float*)d_in[3];
    const float* Wq      = (const float*)d_in[4];
    const float* Wk      = (const float*)d_in[5];
    const float* Wv      = (const float*)d_in[6];
    const float* Wp      = (const float*)d_in[7];
    const float* bp      = (const float*)d_in[8];
    float* out = (float*)d_out;

    // ws: qp 4MB | kp 4MB | vp 4MB | val 4MB | mbias 32KB
    char* wsb = (char*)d_ws;
    f16*   qp_h  = (f16*)(wsb);
    f16*   kp_h  = (f16*)(wsb + (4u << 20));
    f16*   vp_h  = (f16*)(wsb + (8u << 20));
    f16*   val_h = (f16*)(wsb + (12u << 20));
    float* mbias = (float*)(wsb + (16u << 20));

    proj_qkv_kernel<<<dim3(1024), dim3(256), 0, stream>>>(
        queries, keys, values, mask, Wq, Wk, Wv, qp_h, kp_h, vp_h, mbias);
    attn_kernel<<<dim3(1024), dim3(256), 0, stream>>>(
        mbias, qp_h, kp_h, vp_h, val_h);
    outproj_kernel<<<dim3(512), dim3(256), 0, stream>>>(val_h, Wp, bp, mask, out);
}